// Round 5
// baseline (1516.674 us; speedup 1.0000x reference)
//
#include <hip/hip_runtime.h>
#include <math.h>

#define H 128
#define PART_EDGES 4096

typedef __bf16 bf16x8 __attribute__((ext_vector_type(8)));
typedef float f32x4 __attribute__((ext_vector_type(4)));

static __device__ __forceinline__ unsigned short f2bf(float f) {
    unsigned u = __float_as_uint(f);
    unsigned r = 0x7fffu + ((u >> 16) & 1u);
    return (unsigned short)((u + r) >> 16);
}
static __device__ __forceinline__ float bflo(unsigned w) {
    return __uint_as_float(w << 16);
}
static __device__ __forceinline__ float bfhi(unsigned w) {
    return __uint_as_float(w & 0xffff0000u);
}

// ------------------------------------------------------------- degree -------
__global__ void k_zero(int* __restrict__ p, int n) {
    int i = blockIdx.x * blockDim.x + threadIdx.x;
    if (i < n) p[i] = 0;
}

__global__ void k_hist(const int* __restrict__ dst, int* __restrict__ cnt, int E) {
    int e = blockIdx.x * blockDim.x + threadIdx.x;
    if (e < E) atomicAdd(&cnt[dst[e]], 1);
}

__global__ void k_dinv(const int* __restrict__ cnt, float* __restrict__ dinv, int N) {
    int i = blockIdx.x * blockDim.x + threadIdx.x;
    if (i < N) dinv[i] = rsqrtf((float)(cnt[i] + 1));
}

// bucket sizes from per-node counts (bucket = node >> 7)
__global__ void k_bsum(const int* __restrict__ cnt, int* __restrict__ bcnt, int N) {
    int b = blockIdx.x;
    int t = threadIdx.x;  // 128 threads = 2 waves
    int n = (b << 7) + t;
    int v = (n < N) ? cnt[n] : 0;
#pragma unroll
    for (int off = 32; off; off >>= 1) v += __shfl_down(v, off, 64);
    __shared__ int acc2[2];
    if ((t & 63) == 0) acc2[t >> 6] = v;
    __syncthreads();
    if (t == 0) bcnt[b] = acc2[0] + acc2[1];
}

__global__ void k_bscan(const int* __restrict__ bcnt, int* __restrict__ boff,
                        int* __restrict__ bcur, int NBUK) {
    if (threadIdx.x == 0 && blockIdx.x == 0) {
        int run = 0;
        for (int i = 0; i < NBUK; ++i) { boff[i] = run; bcur[i] = run; run += bcnt[i]; }
        boff[NBUK] = run;
    }
}

// --------------------------------------------------- W transpose to bf16 ----
__global__ void k_wt(const float* __restrict__ W, unsigned short* __restrict__ Wt) {
    int t = blockIdx.x * 256 + threadIdx.x;   // 16384 threads
    int j = t >> 7, k = t & 127;
    Wt[(size_t)j * H + k] = f2bf(W[(size_t)k * H + j]);
}

// ------------------- x pre-scale, strided-pair pack: word l = (f_l, f_l+64) -
__global__ void k_xb(const float* __restrict__ x, const float* __restrict__ dinv,
                     unsigned* __restrict__ xb2, int N) {
    int t = blockIdx.x * 256 + threadIdx.x;   // N*64 threads
    if (t >= N * 64) return;
    int n = t >> 6, l = t & 63;
    float s = dinv[n];
    float a = x[(size_t)n * H + l] * s;
    float b = x[(size_t)n * H + 64 + l] * s;
    xb2[t] = (unsigned)f2bf(a) | ((unsigned)f2bf(b) << 16);
}

// -------------------------------------------- bucket partition of edges -----
// record = src | (dst&127)<<17 ; grouped by bucket (dst>>7), block-contiguous
__global__ __launch_bounds__(256) void k_part(const int* __restrict__ ei,
                                              int* __restrict__ bcur,
                                              unsigned* __restrict__ pair, int E) {
    __shared__ int hist[1024];
    __shared__ int base[1024];
    int t = threadIdx.x;
    for (int i = t; i < 1024; i += 256) hist[i] = 0;
    __syncthreads();
    int e0 = blockIdx.x * PART_EDGES;
    int e1 = min(e0 + PART_EDGES, E);
    for (int e = e0 + t; e < e1; e += 256) {
        int d = ei[E + e];
        atomicAdd(&hist[d >> 7], 1);
    }
    __syncthreads();
    for (int i = t; i < 1024; i += 256) {
        int h = hist[i];
        base[i] = h ? atomicAdd(&bcur[i], h) : 0;
        hist[i] = 0;  // reuse as local cursor
    }
    __syncthreads();
    for (int e = e0 + t; e < e1; e += 256) {
        int s = ei[e];
        int d = ei[E + e];
        int b = d >> 7;
        int r = atomicAdd(&hist[b], 1);
        pair[base[b] + r] = (unsigned)s | ((unsigned)(d & 127) << 17);
    }
}

// --------------------------- bucket aggregate: LDS f32 accumulate -----------
// one block per bucket of 128 nodes; acc[d][f] (64KB); self term pre-loaded.
__global__ __launch_bounds__(512) void k_bagg(const unsigned* __restrict__ xb2,
                                              const unsigned* __restrict__ pair,
                                              const int* __restrict__ boff,
                                              const float* __restrict__ dinv,
                                              unsigned* __restrict__ aggb2, int N) {
    __shared__ float acc[128 * 128];  // 64 KB
    int b  = blockIdx.x;
    int t  = threadIdx.x;
    int n0 = b << 7;

    // init with self-loop term xb[n]
    for (int i = t; i < 8192; i += 512) {
        int d = i >> 6, l = i & 63;
        int n = n0 + d;
        unsigned w = (n < N) ? xb2[(size_t)n * 64 + l] : 0u;
        acc[d * 128 + l]      = bflo(w);
        acc[d * 128 + l + 64] = bfhi(w);
    }
    __syncthreads();

    int lo = boff[b], hi = boff[b + 1];
    int wv = t >> 6, lane = t & 63;
    for (int j = lo + wv; j < hi; j += 16) {
        int j2 = j + 8;
        bool two = (j2 < hi);
        unsigned w0 = __builtin_amdgcn_readfirstlane(pair[j]);
        unsigned w1 = __builtin_amdgcn_readfirstlane(two ? pair[j2] : 0u);
        int s0 = w0 & 0x1FFFF, d0 = w0 >> 17;
        int s1 = w1 & 0x1FFFF, d1 = w1 >> 17;
        unsigned x0 = xb2[(size_t)s0 * 64 + lane];
        unsigned x1 = two ? xb2[(size_t)s1 * 64 + lane] : 0u;
        atomicAdd(&acc[d0 * 128 + lane],      bflo(x0));
        atomicAdd(&acc[d0 * 128 + lane + 64], bfhi(x0));
        if (two) {
            atomicAdd(&acc[d1 * 128 + lane],      bflo(x1));
            atomicAdd(&acc[d1 * 128 + lane + 64], bfhi(x1));
        }
    }
    __syncthreads();

    // write aggb2 standard layout: word j of node n = feats (2j, 2j+1)
    for (int i = t; i < 8192; i += 512) {
        int d = i >> 6, j = i & 63;
        int n = n0 + d;
        if (n >= N) break;
        float dn = dinv[n];
        float f0 = acc[d * 128 + 2 * j]     * dn;
        float f1 = acc[d * 128 + 2 * j + 1] * dn;
        aggb2[(size_t)n * 64 + j] = (unsigned)f2bf(f0) | ((unsigned)f2bf(f1) << 16);
    }
}

// --------------------------- MFMA GEMM + bias + GELU + LayerNorm ------------
__global__ __launch_bounds__(512) void k_gemm_ln(const unsigned short* __restrict__ aggb,
                                                 const unsigned short* __restrict__ Wt,
                                                 const float* __restrict__ bias,
                                                 const float* __restrict__ gamma,
                                                 const float* __restrict__ beta,
                                                 float* __restrict__ outp,
                                                 int N) {
    __shared__ unsigned short Ws[H * H];  // 32 KB, XOR-swizzled rows
    {
        const unsigned* src = (const unsigned*)Wt;
#pragma unroll
        for (int i = 0; i < 16; ++i) {
            int idx = threadIdx.x + i * 512;
            unsigned v = src[idx];
            int j = idx >> 6;
            int byte = (idx << 2) ^ ((j & 7) << 4);
            *(unsigned*)((char*)Ws + byte) = v;
        }
    }
    __syncthreads();

    const int wv   = threadIdx.x >> 6;
    const int lane = threadIdx.x & 63;
    const int g    = lane >> 4;
    const int c    = lane & 15;
    const int r0   = blockIdx.x * 128 + wv * 16;
    if (r0 >= N) return;

    float bc[8], gc[8], bec[8];
#pragma unroll
    for (int ct = 0; ct < 8; ++ct) {
        int col = ct * 16 + c;
        bc[ct]  = bias[col];
        gc[ct]  = gamma[col];
        bec[ct] = beta[col];
    }

    f32x4 acc[8];
#pragma unroll
    for (int ct = 0; ct < 8; ++ct) acc[ct] = (f32x4){0.f, 0.f, 0.f, 0.f};

#pragma unroll
    for (int ks = 0; ks < 4; ++ks) {
        int ar = r0 + c; if (ar >= N) ar = N - 1;
        bf16x8 af = *(const bf16x8*)(aggb + (size_t)ar * H + ks * 32 + g * 8);
#pragma unroll
        for (int ct = 0; ct < 8; ++ct) {
            int j = ct * 16 + c;
            int byte = (j * 256 + ks * 64 + g * 16) ^ ((j & 7) << 4);
            bf16x8 bf = *(const bf16x8*)((const char*)Ws + byte);
            acc[ct] = __builtin_amdgcn_mfma_f32_16x16x32_bf16(af, bf, acc[ct], 0, 0, 0);
        }
    }

#pragma unroll
    for (int q = 0; q < 4; ++q) {
        int row = r0 + g * 4 + q;
        float v[8];
        float s = 0.f, sq = 0.f;
#pragma unroll
        for (int ct = 0; ct < 8; ++ct) {
            float t = acc[ct][q] + bc[ct];
            t = 0.5f * t * (1.0f + erff(t * 0.70710678118654752f));
            v[ct] = t;
            s += t;
            sq += t * t;
        }
#pragma unroll
        for (int off = 8; off > 0; off >>= 1) {
            s  += __shfl_xor(s,  off, 64);
            sq += __shfl_xor(sq, off, 64);
        }
        float mu  = s * (1.0f / H);
        float var = sq * (1.0f / H) - mu * mu;
        float rs  = rsqrtf(var + 1e-5f);
        if (row < N) {
            float* op = outp + (size_t)row * H;
#pragma unroll
            for (int ct = 0; ct < 8; ++ct) {
                op[ct * 16 + c] = (v[ct] - mu) * rs * gc[ct] + bec[ct];
            }
        }
    }
}

// ---------------------------------------------------------------- launch ----
extern "C" void kernel_launch(void* const* d_in, const int* in_sizes, int n_in,
                              void* d_out, int out_size, void* d_ws, size_t ws_size,
                              hipStream_t stream) {
    const float* x     = (const float*)d_in[0];
    const int*   ei    = (const int*)d_in[1];
    const float* W     = (const float*)d_in[2];
    const float* b     = (const float*)d_in[3];
    const float* gamma = (const float*)d_in[4];
    const float* beta  = (const float*)d_in[5];
    float* out = (float*)d_out;

    const int N = in_sizes[0] / H;
    const int E = in_sizes[1] / 2;
    const int NBUK = (N + 127) / 128;

    // workspace layout (aligned to 256 B between arrays)
    char* w = (char*)d_ws;
    auto alloc = [&](size_t bytes) {
        char* p = w;
        w += (bytes + 255) & ~(size_t)255;
        return p;
    };
    int*   cnt  = (int*)alloc((size_t)N * 4);
    float* dinv = (float*)alloc((size_t)N * 4);
    int*   bcnt = (int*)alloc((size_t)NBUK * 4);
    int*   boff = (int*)alloc((size_t)(NBUK + 1) * 4);
    int*   bcur = (int*)alloc((size_t)NBUK * 4);
    unsigned* pair = (unsigned*)alloc((size_t)E * 4);
    unsigned short* Wt = (unsigned short*)alloc((size_t)H * H * 2);
    unsigned* aggb2 = (unsigned*)alloc((size_t)N * 64 * 4);

    // xb (bf16 strided-pair packed x*dinv) in the first half of d_out;
    // fully consumed by k_bagg before k_gemm_ln overwrites d_out.
    unsigned* xb2 = (unsigned*)d_out;

    k_wt   <<<(H * H) / 256, 256, 0, stream>>>(W, Wt);

    k_zero <<<(N + 255) / 256, 256, 0, stream>>>(cnt, N);
    k_hist <<<(E + 255) / 256, 256, 0, stream>>>(ei + E, cnt, E);
    k_dinv <<<(N + 255) / 256, 256, 0, stream>>>(cnt, dinv, N);
    k_bsum <<<NBUK, 128, 0, stream>>>(cnt, bcnt, N);
    k_bscan<<<1, 64, 0, stream>>>(bcnt, boff, bcur, NBUK);
    k_xb   <<<(N * 64 + 255) / 256, 256, 0, stream>>>(x, dinv, xb2, N);
    k_part <<<(E + PART_EDGES - 1) / PART_EDGES, 256, 0, stream>>>(ei, bcur, pair, E);

    k_bagg <<<NBUK, 512, 0, stream>>>(xb2, pair, boff, dinv, aggb2, N);

    k_gemm_ln<<<(N + 127) / 128, 512, 0, stream>>>((const unsigned short*)aggb2, Wt,
                                                   b, gamma, beta, out, N);
}

// Round 6
// 252.582 us; speedup vs baseline: 6.0047x; 6.0047x over previous
//
#include <hip/hip_runtime.h>
#include <math.h>

#define H 128
#define PART_EDGES 4096
#define SORT_LDS 4096

typedef __bf16 bf16x8 __attribute__((ext_vector_type(8)));
typedef float f32x4 __attribute__((ext_vector_type(4)));

static __device__ __forceinline__ unsigned short f2bf(float f) {
    unsigned u = __float_as_uint(f);
    unsigned r = 0x7fffu + ((u >> 16) & 1u);
    return (unsigned short)((u + r) >> 16);
}
static __device__ __forceinline__ float bflo(unsigned w) {
    return __uint_as_float(w << 16);
}
static __device__ __forceinline__ float bfhi(unsigned w) {
    return __uint_as_float(w & 0xffff0000u);
}

// ------------------------------------------------------------- degree -------
__global__ void k_zero(int* __restrict__ p, int n) {
    int i = blockIdx.x * blockDim.x + threadIdx.x;
    if (i < n) p[i] = 0;
}

__global__ void k_hist(const int* __restrict__ dst, int* __restrict__ cnt, int E) {
    int e = blockIdx.x * blockDim.x + threadIdx.x;
    if (e < E) atomicAdd(&cnt[dst[e]], 1);
}

__global__ void k_dinv(const int* __restrict__ cnt, float* __restrict__ dinv, int N) {
    int i = blockIdx.x * blockDim.x + threadIdx.x;
    if (i < N) dinv[i] = rsqrtf((float)(cnt[i] + 1));
}

// bucket sizes from per-node counts (bucket = node >> 7)
__global__ void k_bsum(const int* __restrict__ cnt, int* __restrict__ bcnt, int N) {
    int b = blockIdx.x;
    int t = threadIdx.x;  // 128 threads = 2 waves
    int n = (b << 7) + t;
    int v = (n < N) ? cnt[n] : 0;
#pragma unroll
    for (int off = 32; off; off >>= 1) v += __shfl_down(v, off, 64);
    __shared__ int acc2[2];
    if ((t & 63) == 0) acc2[t >> 6] = v;
    __syncthreads();
    if (t == 0) bcnt[b] = acc2[0] + acc2[1];
}

__global__ void k_bscan(const int* __restrict__ bcnt, int* __restrict__ boff,
                        int* __restrict__ bcur, int* __restrict__ rowp,
                        int NBUK, int N, int E) {
    if (threadIdx.x == 0 && blockIdx.x == 0) {
        int run = 0;
        for (int i = 0; i < NBUK; ++i) { boff[i] = run; bcur[i] = run; run += bcnt[i]; }
        boff[NBUK] = run;
        rowp[N] = E;
    }
}

// --------------------------------------------------- W transpose to bf16 ----
__global__ void k_wt(const float* __restrict__ W, unsigned short* __restrict__ Wt) {
    int t = blockIdx.x * 256 + threadIdx.x;   // 16384 threads
    int j = t >> 7, k = t & 127;
    Wt[(size_t)j * H + k] = f2bf(W[(size_t)k * H + j]);
}

// ------------------- x pre-scale: word w = bf16 pair (feat 2w, 2w+1) --------
__global__ void k_xb(const float* __restrict__ x, const float* __restrict__ dinv,
                     unsigned* __restrict__ xb2, int N) {
    int t = blockIdx.x * 256 + threadIdx.x;   // N*32 threads
    if (t >= N * 32) return;
    int n = t >> 5;
    float s = dinv[n];
    float4 v = ((const float4*)x)[t];
    uint2 o;
    o.x = (unsigned)f2bf(v.x * s) | ((unsigned)f2bf(v.y * s) << 16);
    o.y = (unsigned)f2bf(v.z * s) | ((unsigned)f2bf(v.w * s) << 16);
    ((uint2*)xb2)[t] = o;
}

// -------------------------------------------- bucket partition of edges -----
// record = src | (dst&127)<<17 ; grouped by bucket (dst>>7)
__global__ __launch_bounds__(256) void k_part(const int* __restrict__ ei,
                                              int* __restrict__ bcur,
                                              unsigned* __restrict__ pair, int E) {
    __shared__ int hist[1024];
    __shared__ int base[1024];
    int t = threadIdx.x;
    for (int i = t; i < 1024; i += 256) hist[i] = 0;
    __syncthreads();
    int e0 = blockIdx.x * PART_EDGES;
    int e1 = min(e0 + PART_EDGES, E);
    for (int e = e0 + t; e < e1; e += 256) {
        int d = ei[E + e];
        atomicAdd(&hist[d >> 7], 1);
    }
    __syncthreads();
    for (int i = t; i < 1024; i += 256) {
        int h = hist[i];
        base[i] = h ? atomicAdd(&bcur[i], h) : 0;
        hist[i] = 0;  // reuse as local cursor
    }
    __syncthreads();
    for (int e = e0 + t; e < e1; e += 256) {
        int s = ei[e];
        int d = ei[E + e];
        int b = d >> 7;
        int r = atomicAdd(&hist[b], 1);
        pair[base[b] + r] = (unsigned)s | ((unsigned)(d & 127) << 17);
    }
}

// ------------------------------ bucket-local counting sort -> ssrc, rowp ----
// one block per bucket; coalesced contiguous output writes
__global__ __launch_bounds__(256) void k_sort(const unsigned* __restrict__ pair,
                                              const int* __restrict__ boff,
                                              int* __restrict__ rowp,
                                              int* __restrict__ ssrc, int N) {
    __shared__ int hist[128];
    __shared__ int lofs[128];
    __shared__ int cur[128];
    __shared__ int sl[SORT_LDS];
    int b = blockIdx.x;
    int t = threadIdx.x;
    int lo = boff[b], hi = boff[b + 1];
    int cntE = hi - lo;
    if (t < 128) hist[t] = 0;
    __syncthreads();
    for (int i = t; i < cntE; i += 256) {
        unsigned w = pair[lo + i];
        atomicAdd(&hist[w >> 17], 1);
    }
    __syncthreads();
    if (t == 0) {
        int run = 0;
        for (int d = 0; d < 128; ++d) { lofs[d] = run; cur[d] = run; run += hist[d]; }
    }
    __syncthreads();
    int n0 = b << 7;
    if (t < 128 && n0 + t < N) rowp[n0 + t] = lo + lofs[t];
    for (int i = t; i < cntE; i += 256) {
        unsigned w = pair[lo + i];
        int d = w >> 17;
        int s = (int)(w & 0x1FFFF);
        int pos = atomicAdd(&cur[d], 1);
        if (pos < SORT_LDS) sl[pos] = s;
        else ssrc[lo + pos] = s;   // statistically never; correctness fallback
    }
    __syncthreads();
    int lim = min(cntE, SORT_LDS);
    for (int i = t; i < lim; i += 256) ssrc[lo + i] = sl[i];
}

// ------------------------------------------------------ gather aggregate ----
// one wave per node: aggb[n] = bf16( dinv[n] * (xb[n] + sum_e xb[src_e]) )
__global__ __launch_bounds__(256) void k_agg(const unsigned* __restrict__ xb2,
                                             const int* __restrict__ rowp,
                                             const int* __restrict__ ssrc,
                                             const float* __restrict__ dinv,
                                             unsigned* __restrict__ aggb2, int N) {
    int n = blockIdx.x * 4 + (threadIdx.x >> 6);
    if (n >= N) return;
    int lane = threadIdx.x & 63;

    int lo = __builtin_amdgcn_readfirstlane(rowp[n]);
    int hi = __builtin_amdgcn_readfirstlane(rowp[n + 1]);
    float dn = dinv[n];

    unsigned w = xb2[(size_t)n * 64 + lane];
    float accx = bflo(w), accy = bfhi(w);

    int j = lo;
    for (; j + 4 <= hi; j += 4) {
        int s0 = __builtin_amdgcn_readfirstlane(ssrc[j]);
        int s1 = __builtin_amdgcn_readfirstlane(ssrc[j + 1]);
        int s2 = __builtin_amdgcn_readfirstlane(ssrc[j + 2]);
        int s3 = __builtin_amdgcn_readfirstlane(ssrc[j + 3]);
        unsigned w0 = xb2[(size_t)s0 * 64 + lane];
        unsigned w1 = xb2[(size_t)s1 * 64 + lane];
        unsigned w2 = xb2[(size_t)s2 * 64 + lane];
        unsigned w3 = xb2[(size_t)s3 * 64 + lane];
        accx += bflo(w0) + bflo(w1) + bflo(w2) + bflo(w3);
        accy += bfhi(w0) + bfhi(w1) + bfhi(w2) + bfhi(w3);
    }
    for (; j < hi; ++j) {
        int s0 = __builtin_amdgcn_readfirstlane(ssrc[j]);
        unsigned w0 = xb2[(size_t)s0 * 64 + lane];
        accx += bflo(w0);
        accy += bfhi(w0);
    }
    aggb2[(size_t)n * 64 + lane] =
        (unsigned)f2bf(accx * dn) | ((unsigned)f2bf(accy * dn) << 16);
}

// --------------------------- MFMA GEMM + bias + GELU + LayerNorm ------------
__global__ __launch_bounds__(512) void k_gemm_ln(const unsigned short* __restrict__ aggb,
                                                 const unsigned short* __restrict__ Wt,
                                                 const float* __restrict__ bias,
                                                 const float* __restrict__ gamma,
                                                 const float* __restrict__ beta,
                                                 float* __restrict__ outp,
                                                 int N) {
    __shared__ unsigned short Ws[H * H];  // 32 KB, XOR-swizzled rows
    {
        const unsigned* src = (const unsigned*)Wt;
#pragma unroll
        for (int i = 0; i < 16; ++i) {
            int idx = threadIdx.x + i * 512;
            unsigned v = src[idx];
            int j = idx >> 6;
            int byte = (idx << 2) ^ ((j & 7) << 4);
            *(unsigned*)((char*)Ws + byte) = v;
        }
    }
    __syncthreads();

    const int wv   = threadIdx.x >> 6;
    const int lane = threadIdx.x & 63;
    const int g    = lane >> 4;
    const int c    = lane & 15;
    const int r0   = blockIdx.x * 128 + wv * 16;
    if (r0 >= N) return;

    float bc[8], gc[8], bec[8];
#pragma unroll
    for (int ct = 0; ct < 8; ++ct) {
        int col = ct * 16 + c;
        bc[ct]  = bias[col];
        gc[ct]  = gamma[col];
        bec[ct] = beta[col];
    }

    f32x4 acc[8];
#pragma unroll
    for (int ct = 0; ct < 8; ++ct) acc[ct] = (f32x4){0.f, 0.f, 0.f, 0.f};

#pragma unroll
    for (int ks = 0; ks < 4; ++ks) {
        int ar = r0 + c; if (ar >= N) ar = N - 1;
        bf16x8 af = *(const bf16x8*)(aggb + (size_t)ar * H + ks * 32 + g * 8);
#pragma unroll
        for (int ct = 0; ct < 8; ++ct) {
            int j = ct * 16 + c;
            int byte = (j * 256 + ks * 64 + g * 16) ^ ((j & 7) << 4);
            bf16x8 bf = *(const bf16x8*)((const char*)Ws + byte);
            acc[ct] = __builtin_amdgcn_mfma_f32_16x16x32_bf16(af, bf, acc[ct], 0, 0, 0);
        }
    }

#pragma unroll
    for (int q = 0; q < 4; ++q) {
        int row = r0 + g * 4 + q;
        float v[8];
        float s = 0.f, sq = 0.f;
#pragma unroll
        for (int ct = 0; ct < 8; ++ct) {
            float t = acc[ct][q] + bc[ct];
            t = 0.5f * t * (1.0f + erff(t * 0.70710678118654752f));
            v[ct] = t;
            s += t;
            sq += t * t;
        }
#pragma unroll
        for (int off = 8; off > 0; off >>= 1) {
            s  += __shfl_xor(s,  off, 64);
            sq += __shfl_xor(sq, off, 64);
        }
        float mu  = s * (1.0f / H);
        float var = sq * (1.0f / H) - mu * mu;
        float rs  = rsqrtf(var + 1e-5f);
        if (row < N) {
            float* op = outp + (size_t)row * H;
#pragma unroll
            for (int ct = 0; ct < 8; ++ct) {
                op[ct * 16 + c] = (v[ct] - mu) * rs * gc[ct] + bec[ct];
            }
        }
    }
}

// ---------------------------------------------------------------- launch ----
extern "C" void kernel_launch(void* const* d_in, const int* in_sizes, int n_in,
                              void* d_out, int out_size, void* d_ws, size_t ws_size,
                              hipStream_t stream) {
    const float* x     = (const float*)d_in[0];
    const int*   ei    = (const int*)d_in[1];
    const float* W     = (const float*)d_in[2];
    const float* b     = (const float*)d_in[3];
    const float* gamma = (const float*)d_in[4];
    const float* beta  = (const float*)d_in[5];
    float* out = (float*)d_out;

    const int N = in_sizes[0] / H;
    const int E = in_sizes[1] / 2;
    const int NBUK = (N + 127) / 128;

    // workspace layout (256 B aligned between arrays)
    char* w = (char*)d_ws;
    auto alloc = [&](size_t bytes) {
        char* p = w;
        w += (bytes + 255) & ~(size_t)255;
        return p;
    };
    int*   cnt  = (int*)alloc((size_t)N * 4);
    float* dinv = (float*)alloc((size_t)N * 4);
    int*   bcnt = (int*)alloc((size_t)NBUK * 4);
    int*   boff = (int*)alloc((size_t)(NBUK + 1) * 4);
    int*   bcur = (int*)alloc((size_t)NBUK * 4);
    int*   rowp = (int*)alloc((size_t)(N + 1) * 4);
    int*   ssrc = (int*)alloc((size_t)E * 4);
    unsigned short* Wt = (unsigned short*)alloc((size_t)H * H * 2);
    unsigned* aggb2 = (unsigned*)alloc((size_t)N * 64 * 4);

    // d_out staging: first half = xb2 (bf16 x*dinv), upper part = pair records.
    // Both fully consumed before k_gemm_ln overwrites d_out.
    unsigned* xb2  = (unsigned*)d_out;             // N*64 u32
    unsigned* pair = (unsigned*)d_out + (size_t)N * 64;  // E u32

    k_wt   <<<(H * H) / 256, 256, 0, stream>>>(W, Wt);

    k_zero <<<(N + 255) / 256, 256, 0, stream>>>(cnt, N);
    k_hist <<<(E + 255) / 256, 256, 0, stream>>>(ei + E, cnt, E);
    k_dinv <<<(N + 255) / 256, 256, 0, stream>>>(cnt, dinv, N);
    k_bsum <<<NBUK, 128, 0, stream>>>(cnt, bcnt, N);
    k_bscan<<<1, 64, 0, stream>>>(bcnt, boff, bcur, rowp, NBUK, N, E);
    k_xb   <<<(N * 32 + 255) / 256, 256, 0, stream>>>(x, dinv, xb2, N);
    k_part <<<(E + PART_EDGES - 1) / PART_EDGES, 256, 0, stream>>>(ei, bcur, pair, E);
    k_sort <<<NBUK, 256, 0, stream>>>(pair, boff, rowp, ssrc, N);

    k_agg  <<<(N + 3) / 4, 256, 0, stream>>>(xb2, rowp, ssrc, dinv, aggb2, N);

    k_gemm_ln<<<(N + 127) / 128, 512, 0, stream>>>((const unsigned short*)aggb2, Wt,
                                                   b, gamma, beta, out, N);
}